// Round 2
// baseline (163.771 us; speedup 1.0000x reference)
//
#include <hip/hip_runtime.h>
#include <hip/hip_bf16.h>
#include <math.h>

// Problem constants (fixed by reference)
#define NN 8192
#define FF 256
#define ALPHA 0.2f
#define CAP 1024   // max edges/row we track; E[nnz]=82, sigma=9 -> 1024 is >100 sigma

typedef float f32x4 __attribute__((ext_vector_type(4)));  // native vec for nontemporal builtin

// ---------------------------------------------------------------------------
// Kernel 1: p_src[k] = sum_c attn_src[c]*W[c,k]; p_dst likewise.
// One block, 256 threads (thread = k). Coalesced W column reads.
// ---------------------------------------------------------------------------
__global__ __launch_bounds__(256) void prep_kernel(
    const float* __restrict__ W, const float* __restrict__ asrc,
    const float* __restrict__ adst, float* __restrict__ pvec) {
  const int k = threadIdx.x;
  float s = 0.f, d = 0.f;
  for (int c = 0; c < FF; ++c) {
    float w = W[c * FF + k];
    s = fmaf(asrc[c], w, s);
    d = fmaf(adst[c], w, d);
  }
  pvec[k] = s;
  pvec[FF + k] = d;
}

// ---------------------------------------------------------------------------
// Kernel 2: h = x @ W^T (written as bf16), a_src[i] = x[i]·p_src,
// a_dst[i] = x[i]·p_dst (fp32, exact path for the softmax scores).
// Block = 16 rows, 256 threads (thread = output channel c).
// ---------------------------------------------------------------------------
__global__ __launch_bounds__(256) void gemm_h_kernel(
    const float* __restrict__ x, const float* __restrict__ W,
    const float* __restrict__ pvec, float* __restrict__ a_src,
    float* __restrict__ a_dst, __hip_bfloat16* __restrict__ h_bf) {
  __shared__ float4 xt4[16 * 64];   // 16 rows x 256 cols fp32 (16 KB)
  __shared__ float pv[2 * FF];      // p_src | p_dst (2 KB)
  const int t = threadIdx.x;
  const int i0 = blockIdx.x * 16;

  const float4* x4 = reinterpret_cast<const float4*>(x);
#pragma unroll
  for (int q = 0; q < 4; ++q) {
    int idx = q * 256 + t;
    xt4[idx] = x4[(size_t)i0 * 64 + idx];
  }
  pv[t] = pvec[t];
  pv[FF + t] = pvec[FF + t];
  __syncthreads();

  // a_src / a_dst: 16 threads per row, shuffle-reduce within 16-group
  {
    const float* xt = reinterpret_cast<const float*>(xt4);
    const int r = t >> 4, p = t & 15;
    float ps = 0.f, pd = 0.f;
#pragma unroll
    for (int kk = 0; kk < 16; ++kk) {
      int k = p * 16 + kk;
      float xv = xt[r * 256 + k];
      ps = fmaf(xv, pv[k], ps);
      pd = fmaf(xv, pv[FF + k], pd);
    }
    for (int off = 8; off; off >>= 1) {
      ps += __shfl_down(ps, off, 16);
      pd += __shfl_down(pd, off, 16);
    }
    if (p == 0) { a_src[i0 + r] = ps; a_dst[i0 + r] = pd; }
  }

  // h tile: thread c computes h[i0+r][c] for r=0..15
  const int c = t;
  float acc[16];
#pragma unroll
  for (int r = 0; r < 16; ++r) acc[r] = 0.f;
  const float4* W4 = reinterpret_cast<const float4*>(W);
  for (int k4 = 0; k4 < 64; ++k4) {
    float4 w4 = W4[(size_t)c * 64 + k4];
#pragma unroll
    for (int r = 0; r < 16; ++r) {
      float4 xv = xt4[r * 64 + k4];   // broadcast within wave
      acc[r] = fmaf(w4.x, xv.x, acc[r]);
      acc[r] = fmaf(w4.y, xv.y, acc[r]);
      acc[r] = fmaf(w4.z, xv.z, acc[r]);
      acc[r] = fmaf(w4.w, xv.w, acc[r]);
    }
  }
#pragma unroll
  for (int r = 0; r < 16; ++r)
    h_bf[(size_t)(i0 + r) * FF + c] = __float2bfloat16(acc[r]);
}

// ---------------------------------------------------------------------------
// Kernel 3: one block per destination row i. Streams the adj row once
// (nontemporal f32x4), builds sparse edge list in LDS, exact masked-softmax
// semantics, then 256 threads = 256 channels aggregate w @ h_bf, ELU.
// ---------------------------------------------------------------------------
__global__ __launch_bounds__(256) void attn_kernel(
    const float* __restrict__ adj, const float* __restrict__ a_src,
    const float* __restrict__ a_dst, const __hip_bfloat16* __restrict__ h_bf,
    float* __restrict__ out) {
  __shared__ int s_idx[CAP];
  __shared__ float s_val[CAP];
  __shared__ float red[256];
  __shared__ int s_cnt;
  const int t = threadIdx.x;
  const int i = blockIdx.x;

  if (t == 0) s_cnt = 0;
  __syncthreads();

  const float a_d = a_dst[i];
  const f32x4* adj4 = reinterpret_cast<const f32x4*>(adj + (size_t)i * NN);
  float lmax = -INFINITY;
#pragma unroll
  for (int chunk = 0; chunk < 8; ++chunk) {
    f32x4 v = __builtin_nontemporal_load(adj4 + chunk * 256 + t);
    int jbase = (chunk * 256 + t) * 4;
#pragma unroll
    for (int u = 0; u < 4; ++u) {
      if (v[u] > 0.f) {
        int j = jbase + u;
        float s = a_src[j] + a_d;
        float lk = s > 0.f ? s : ALPHA * s;
        lmax = fmaxf(lmax, lk);
        int pos = atomicAdd(&s_cnt, 1);
        if (pos < CAP) { s_idx[pos] = j; s_val[pos] = lk; }
      }
    }
  }

  // block max
  red[t] = lmax;
  __syncthreads();
  for (int sft = 128; sft; sft >>= 1) {
    if (t < sft) red[t] = fmaxf(red[t], red[t + sft]);
    __syncthreads();
  }
  int cnt = s_cnt;
  if (cnt > CAP) cnt = CAP;
  float m = red[0];
  // masked-out entries contribute exact 0.0 to the row max in the reference
  if (cnt < NN) m = fmaxf(m, 0.f);
  __syncthreads();  // red about to be reused

  // exp + block sum
  float lsum = 0.f;
  for (int p = t; p < cnt; p += 256) {
    float e = __expf(s_val[p] - m);
    s_val[p] = e;
    lsum += e;
  }
  red[t] = lsum;
  __syncthreads();
  for (int sft = 128; sft; sft >>= 1) {
    if (t < sft) red[t] += red[t + sft];
    __syncthreads();
  }
  const float denom = red[0] + 1e-8f;

  // aggregation: thread t = channel c
  float acc = 0.f;
  int p = 0;
  for (; p + 4 <= cnt; p += 4) {
    int j0 = s_idx[p + 0], j1 = s_idx[p + 1], j2 = s_idx[p + 2], j3 = s_idx[p + 3];
    float w0 = s_val[p + 0], w1 = s_val[p + 1], w2 = s_val[p + 2], w3 = s_val[p + 3];
    float v0 = __bfloat162float(h_bf[(size_t)j0 * FF + t]);
    float v1 = __bfloat162float(h_bf[(size_t)j1 * FF + t]);
    float v2 = __bfloat162float(h_bf[(size_t)j2 * FF + t]);
    float v3 = __bfloat162float(h_bf[(size_t)j3 * FF + t]);
    acc = fmaf(w0, v0, acc);
    acc = fmaf(w1, v1, acc);
    acc = fmaf(w2, v2, acc);
    acc = fmaf(w3, v3, acc);
  }
  for (; p < cnt; ++p)
    acc = fmaf(s_val[p], __bfloat162float(h_bf[(size_t)s_idx[p] * FF + t]), acc);

  float o = acc / denom;
  out[(size_t)i * FF + t] = o > 0.f ? o : (__expf(o) - 1.f);
}

// ---------------------------------------------------------------------------
extern "C" void kernel_launch(void* const* d_in, const int* in_sizes, int n_in,
                              void* d_out, int out_size, void* d_ws, size_t ws_size,
                              hipStream_t stream) {
  const float* x        = (const float*)d_in[0];   // (8192,256)
  const float* adj      = (const float*)d_in[1];   // (8192,8192)
  const float* W        = (const float*)d_in[2];   // (256,256)
  const float* attn_src = (const float*)d_in[3];   // (1,256)
  const float* attn_dst = (const float*)d_in[4];   // (1,256)
  float* out = (float*)d_out;                      // (8192,256) fp32

  // ws layout: pvec (512 f32) | a_src (8192 f32) | a_dst (8192 f32) | h_bf (8192*256 bf16)
  char* ws = (char*)d_ws;
  float* pvec  = (float*)ws;                        // 2 KB
  float* a_src = (float*)(ws + 2048);               // 32 KB
  float* a_dst = (float*)(ws + 2048 + 32768);       // 32 KB
  __hip_bfloat16* h_bf = (__hip_bfloat16*)(ws + 2048 + 65536);  // 4 MB

  hipLaunchKernelGGL(prep_kernel, dim3(1), dim3(256), 0, stream,
                     W, attn_src, attn_dst, pvec);
  hipLaunchKernelGGL(gemm_h_kernel, dim3(NN / 16), dim3(256), 0, stream,
                     x, W, pvec, a_src, a_dst, h_bf);
  hipLaunchKernelGGL(attn_kernel, dim3(NN), dim3(256), 0, stream,
                     adj, a_src, a_dst, h_bf, out);
}

// Round 3
// 120.757 us; speedup vs baseline: 1.3562x; 1.3562x over previous
//
#include <hip/hip_runtime.h>
#include <hip/hip_bf16.h>
#include <math.h>

// Problem constants (fixed by reference)
#define NN 8192
#define FF 256
#define ALPHA 0.2f
#define CAP 1024   // max edges/row tracked; E[nnz]=82, sd=9 -> 1024 is >100 sigma

typedef float f32x4 __attribute__((ext_vector_type(4)));

// ---------------------------------------------------------------------------
// Kernel 1: h = x @ W^T (bf16 out), plus a_src[i] = h[i]·attn_src,
// a_dst[i] = h[i]·attn_dst computed from the fp32 accumulators (no prep pass).
// Block = 16 rows, 256 threads (thread = output channel c).
// ---------------------------------------------------------------------------
__global__ __launch_bounds__(256) void gemm_h_kernel(
    const float* __restrict__ x, const float* __restrict__ W,
    const float* __restrict__ asrc, const float* __restrict__ adst,
    float* __restrict__ a_src, float* __restrict__ a_dst,
    __hip_bfloat16* __restrict__ h_bf) {
  __shared__ float4 xt4[16 * 64];     // 16 rows x 256 cols fp32 (16 KB)
  __shared__ float pr[2][16][4];      // per-row per-wave partials (src,dst)
  const int t = threadIdx.x;
  const int lane = t & 63, wid = t >> 6;
  const int i0 = blockIdx.x * 16;

  const float4* x4 = reinterpret_cast<const float4*>(x);
#pragma unroll
  for (int q = 0; q < 4; ++q) {
    int idx = q * 256 + t;
    xt4[idx] = x4[(size_t)i0 * 64 + idx];
  }
  __syncthreads();

  // h tile: thread c computes h[i0+r][c] for r=0..15
  const int c = t;
  const float asv = asrc[c];
  const float adv = adst[c];
  float acc[16];
#pragma unroll
  for (int r = 0; r < 16; ++r) acc[r] = 0.f;
  const float4* W4 = reinterpret_cast<const float4*>(W);
  for (int k4 = 0; k4 < 64; ++k4) {
    float4 w4 = W4[(size_t)c * 64 + k4];
#pragma unroll
    for (int r = 0; r < 16; ++r) {
      float4 xv = xt4[r * 64 + k4];   // uniform across wave -> LDS broadcast
      acc[r] = fmaf(w4.x, xv.x, acc[r]);
      acc[r] = fmaf(w4.y, xv.y, acc[r]);
      acc[r] = fmaf(w4.z, xv.z, acc[r]);
      acc[r] = fmaf(w4.w, xv.w, acc[r]);
    }
  }

  // write h as bf16
#pragma unroll
  for (int r = 0; r < 16; ++r)
    h_bf[(size_t)(i0 + r) * FF + c] = __float2bfloat16(acc[r]);

  // a_src/a_dst: block-reduce acc[r]*attn_vec[c] over the 256 channels
#pragma unroll
  for (int r = 0; r < 16; ++r) {
    float ps = acc[r] * asv;
    float pd = acc[r] * adv;
#pragma unroll
    for (int o = 32; o; o >>= 1) {
      ps += __shfl_down(ps, o, 64);
      pd += __shfl_down(pd, o, 64);
    }
    if (lane == 0) { pr[0][r][wid] = ps; pr[1][r][wid] = pd; }
  }
  __syncthreads();
  if (t < 32) {
    int r = t & 15, which = t >> 4;
    float s4 = pr[which][r][0] + pr[which][r][1] + pr[which][r][2] + pr[which][r][3];
    if (which == 0) a_src[i0 + r] = s4;
    else            a_dst[i0 + r] = s4;
  }
}

// ---------------------------------------------------------------------------
// Kernel 2: one block per destination row i.
// Phase A: 8 back-to-back nontemporal f32x4 loads -> branchless 32-bit hit
//          mask per thread (no atomics, no gathers interleaved with stream).
// Phase B: shuffle prefix-scan compaction into LDS edge list (deterministic).
// Phase C: dense score/max/exp/sum over the compacted list.
// Phase D: thread=channel aggregation over ~82 edges from L2-resident h_bf.
// ---------------------------------------------------------------------------
__global__ __launch_bounds__(256) void attn_kernel(
    const float* __restrict__ adj, const float* __restrict__ a_src,
    const float* __restrict__ a_dst, const __hip_bfloat16* __restrict__ h_bf,
    float* __restrict__ out) {
  __shared__ int s_idx[CAP];
  __shared__ float s_val[CAP];
  __shared__ float red[256];
  __shared__ int wsum[4];
  const int t = threadIdx.x;
  const int lane = t & 63, wid = t >> 6;
  const int i = blockIdx.x;

  const float a_d = a_dst[i];
  const f32x4* adj4 = reinterpret_cast<const f32x4*>(adj + (size_t)i * NN);

  // Phase A: stream the row, build hit mask branchlessly
  f32x4 v[8];
#pragma unroll
  for (int ch = 0; ch < 8; ++ch)
    v[ch] = __builtin_nontemporal_load(adj4 + ch * 256 + t);
  unsigned m = 0u;
#pragma unroll
  for (int ch = 0; ch < 8; ++ch) {
#pragma unroll
    for (int u = 0; u < 4; ++u)
      m |= (v[ch][u] > 0.f ? 1u : 0u) << (ch * 4 + u);
  }

  // Phase B: compaction via wave prefix scan + cross-wave offsets
  const int cnt_t = __popc(m);
  int scan = cnt_t;
#pragma unroll
  for (int d = 1; d < 64; d <<= 1) {
    int nv = __shfl_up(scan, d, 64);
    if (lane >= d) scan += nv;
  }
  if (lane == 63) wsum[wid] = scan;
  __syncthreads();
  int base = 0;
  for (int w = 0; w < wid; ++w) base += wsum[w];
  int cnt = wsum[0] + wsum[1] + wsum[2] + wsum[3];
  int off = base + scan - cnt_t;   // exclusive offset for this thread
  unsigned mm = m;
  while (mm) {
    int b = __builtin_ctz(mm);
    mm &= mm - 1u;
    if (off >= CAP) break;
    // bit b = chunk*4+u -> column j = chunk*1024 + t*4 + u
    s_idx[off++] = ((b >> 2) << 10) + (t << 2) + (b & 3);
  }
  if (cnt > CAP) cnt = CAP;
  __syncthreads();

  // Phase C: scores + max
  float lmax = -INFINITY;
  for (int p = t; p < cnt; p += 256) {
    int j = s_idx[p];
    float s = a_src[j] + a_d;
    float lk = s > 0.f ? s : ALPHA * s;
    s_val[p] = lk;
    lmax = fmaxf(lmax, lk);
  }
  red[t] = lmax;
  __syncthreads();
  for (int sft = 128; sft; sft >>= 1) {
    if (t < sft) red[t] = fmaxf(red[t], red[t + sft]);
    __syncthreads();
  }
  float mx = red[0];
  if (cnt < NN) mx = fmaxf(mx, 0.f);  // masked-out entries are exact 0.0 in ref max
  __syncthreads();

  float lsum = 0.f;
  for (int p = t; p < cnt; p += 256) {
    float e = __expf(s_val[p] - mx);
    s_val[p] = e;
    lsum += e;
  }
  red[t] = lsum;
  __syncthreads();
  for (int sft = 128; sft; sft >>= 1) {
    if (t < sft) red[t] += red[t + sft];
    __syncthreads();
  }
  const float denom = red[0] + 1e-8f;

  // Phase D: aggregation, thread t = channel
  float acc = 0.f;
  int p = 0;
  for (; p + 4 <= cnt; p += 4) {
    int j0 = s_idx[p + 0], j1 = s_idx[p + 1], j2 = s_idx[p + 2], j3 = s_idx[p + 3];
    float w0 = s_val[p + 0], w1 = s_val[p + 1], w2 = s_val[p + 2], w3 = s_val[p + 3];
    float v0 = __bfloat162float(h_bf[(size_t)j0 * FF + t]);
    float v1 = __bfloat162float(h_bf[(size_t)j1 * FF + t]);
    float v2 = __bfloat162float(h_bf[(size_t)j2 * FF + t]);
    float v3 = __bfloat162float(h_bf[(size_t)j3 * FF + t]);
    acc = fmaf(w0, v0, acc);
    acc = fmaf(w1, v1, acc);
    acc = fmaf(w2, v2, acc);
    acc = fmaf(w3, v3, acc);
  }
  for (; p < cnt; ++p)
    acc = fmaf(s_val[p], __bfloat162float(h_bf[(size_t)s_idx[p] * FF + t]), acc);

  float o = acc / denom;
  out[(size_t)i * FF + t] = o > 0.f ? o : (__expf(o) - 1.f);
}

// ---------------------------------------------------------------------------
extern "C" void kernel_launch(void* const* d_in, const int* in_sizes, int n_in,
                              void* d_out, int out_size, void* d_ws, size_t ws_size,
                              hipStream_t stream) {
  const float* x        = (const float*)d_in[0];   // (8192,256)
  const float* adj      = (const float*)d_in[1];   // (8192,8192)
  const float* W        = (const float*)d_in[2];   // (256,256)
  const float* attn_src = (const float*)d_in[3];   // (1,256)
  const float* attn_dst = (const float*)d_in[4];   // (1,256)
  float* out = (float*)d_out;                      // (8192,256) fp32

  // ws layout: a_src (8192 f32) | a_dst (8192 f32) | h_bf (8192*256 bf16)
  char* ws = (char*)d_ws;
  float* a_src = (float*)ws;                                   // 32 KB
  float* a_dst = (float*)(ws + 32768);                         // 32 KB
  __hip_bfloat16* h_bf = (__hip_bfloat16*)(ws + 65536);        // 4 MB

  hipLaunchKernelGGL(gemm_h_kernel, dim3(NN / 16), dim3(256), 0, stream,
                     x, W, attn_src, attn_dst, a_src, a_dst, h_bf);
  hipLaunchKernelGGL(attn_kernel, dim3(NN), dim3(256), 0, stream,
                     adj, a_src, a_dst, h_bf, out);
}